// Round 1
// 1438.235 us; speedup vs baseline: 1.2075x; 1.2075x over previous
//
#include <hip/hip_runtime.h>
#include <hip/hip_bf16.h>
#include <math.h>

#define BB 16
#define TT 128
#define MM 256
#define DD 512
#define HH 8
#define LL 4
#define VV 32000
#define BOS_TOK 32000

typedef __attribute__((ext_vector_type(8))) short s8v;
typedef __attribute__((ext_vector_type(4))) float f4v;

__device__ __forceinline__ float bs2f(short u) {
    union { unsigned int i; float f; } c;
    c.i = ((unsigned int)(unsigned short)u) << 16;
    return c.f;
}
// fp32 -> bf16 bits, round-to-nearest-even (finite inputs only)
__device__ __forceinline__ short f2bs(float f) {
    union { float f; unsigned int u; } c;
    c.f = f;
    unsigned int r = (c.u + 0x7FFFu + ((c.u >> 16) & 1u)) >> 16;
    return (short)r;
}

// ---------------- convert fp32 -> bf16 bits (for `memory`) ----------------
__global__ __launch_bounds__(256) void cvt_k(const float* __restrict__ src,
                                             short* __restrict__ dst, int n4) {
    int i = (blockIdx.x * 256 + threadIdx.x);
    if (i < n4) {
        f4v v = *(const f4v*)&src[i * 4];
#pragma unroll
        for (int j = 0; j < 4; j++) dst[i * 4 + j] = f2bs(v[j]);
    }
}

// ---------------- transpose+convert weights: fp32 [K,N] -> bf16 [N,K] ----------------
// grid: (K/64, N/64, L); z indexes layer (matrix stride K*N both sides)
__global__ __launch_bounds__(256) void wt_k(const float* __restrict__ src,
                                            short* __restrict__ dst, int K, int N) {
    __shared__ short t[64][65];
    int k0 = blockIdx.x * 64, n0 = blockIdx.y * 64;
    size_t zo = (size_t)blockIdx.z * K * N;
    int tid = threadIdx.x;
    int kr = tid >> 2;            // 0..63 (row within K tile)
    int nc = (tid & 3) * 16;      // col group within N tile
    const float* sp = src + zo + (size_t)(k0 + kr) * N + n0 + nc;
#pragma unroll
    for (int c = 0; c < 4; c++) {
        f4v v = *(const f4v*)(sp + c * 4);
#pragma unroll
        for (int j = 0; j < 4; j++) t[kr][nc + c * 4 + j] = f2bs(v[j]);
    }
    __syncthreads();
    int nr = tid >> 2;            // 0..63 (row within N tile)
    int kc = (tid & 3) * 16;
    short* dp = dst + zo + (size_t)(n0 + nr) * K + k0 + kc;
#pragma unroll
    for (int c = 0; c < 2; c++) {
        s8v v;
#pragma unroll
        for (int j = 0; j < 8; j++) v[j] = t[kc + c * 8 + j][nr];
        *(s8v*)(dp + c * 8) = v;
    }
}

// ---------------- embedding: x = tok_emb[inp] + pos_emb[t], fp32 out ----------------
__global__ __launch_bounds__(256) void embed_k(const int* __restrict__ tgt,
                                               const float* __restrict__ tok,
                                               const float* __restrict__ pos,
                                               float* __restrict__ X) {
    int row = blockIdx.x;            // b*T + t
    int t = row & (TT - 1);
    int b = row >> 7;
    int idx = (t == 0) ? BOS_TOK : tgt[b * TT + t - 1];
    const float* te = tok + (size_t)idx * DD;
    const float* pe = pos + (size_t)t * DD;
    float* xr = X + (size_t)row * DD;
    for (int d = threadIdx.x; d < DD; d += 256)
        xr[d] = te[d] + pe[d];
}

// ---------------- layernorm: fp32 x -> bf16 h ----------------
__global__ __launch_bounds__(256) void ln_k(const float* __restrict__ X,
                                            const float* __restrict__ g,
                                            const float* __restrict__ bta,
                                            short* __restrict__ H) {
    int row = blockIdx.x;
    int tid = threadIdx.x;
    const float* xr = X + (size_t)row * DD;
    float v0 = xr[tid], v1 = xr[tid + 256];
    float s = v0 + v1, ss = v0 * v0 + v1 * v1;
    for (int o = 32; o; o >>= 1) {
        s += __shfl_xor(s, o, 64);
        ss += __shfl_xor(ss, o, 64);
    }
    __shared__ float r0[4], r1[4];
    int wave = tid >> 6, lane = tid & 63;
    if (lane == 0) { r0[wave] = s; r1[wave] = ss; }
    __syncthreads();
    s = r0[0] + r0[1] + r0[2] + r0[3];
    ss = r1[0] + r1[1] + r1[2] + r1[3];
    float mean = s * (1.0f / DD);
    float var = ss * (1.0f / DD) - mean * mean;
    float rstd = rsqrtf(var + 1e-5f);
    short* hr = H + (size_t)row * DD;
    hr[tid] = f2bs((v0 - mean) * rstd * g[tid] + bta[tid]);
    hr[tid + 256] = f2bs((v1 - mean) * rstd * g[tid + 256] + bta[tid + 256]);
}

// ---------------- GEMM (bf16 A [M,K] @ bf16 Bt [N,K]) ----------------
// EPI 0: bf16 store to C; 1: gelu(exact) bf16 store; 2: X(fp32) += acc+bias; 3: fp32 store to X
// grid: (M/BM, N/BN) -- x = M tiles (fastest) so same-N blocks are consecutive,
// then XCD chunk swizzle (bijective, m204) gives each XCD a contiguous run of wg:
// the W panel for one N tile is fetched ~once per device instead of once per M tile.
template <int EPI, int BM, int BN>
__global__ __launch_bounds__(256) void gemm_k(const short* __restrict__ A,
                                              const short* __restrict__ Bt,
                                              const float* __restrict__ bias,
                                              short* __restrict__ C,
                                              float* __restrict__ X, int M, int N, int K) {
    constexpr int MI = BM / 32;   // a-frags per wave (wave tile = BM/2 rows)
    constexpr int NJ = BN / 32;   // b-frags per wave (wave tile = BN/2 cols)
    __shared__ short Al[BM * 34]; // pad to 34 shorts (17 dwords, odd) -> conflict-free b128
    __shared__ short Bl[BN * 34];
    int tid = threadIdx.x, lane = tid & 63, wave = tid >> 6;
    int wm = wave >> 1, wn = wave & 1;
    int quad = lane >> 4, l16 = lane & 15;

    // bijective XCD chunk swizzle: orig%8 = XCD; XCD i handles a contiguous chunk of wg
    int nwg = gridDim.x * gridDim.y;
    int orig = blockIdx.y * gridDim.x + blockIdx.x;
    int q = nwg >> 3, r = nwg & 7;
    int xcd = orig & 7, pos = orig >> 3;
    int wg = (xcd < r ? xcd * (q + 1) : r * (q + 1) + (xcd - r) * q) + pos;
    int mt = wg % gridDim.x, nt = wg / gridDim.x;
    int m0 = mt * BM, n0 = nt * BN;

    f4v acc[MI][NJ];
#pragma unroll
    for (int i = 0; i < MI; i++)
#pragma unroll
        for (int j = 0; j < NJ; j++) acc[i][j] = (f4v){0.f, 0.f, 0.f, 0.f};

    constexpr int TPRA = 256 / BM;    // threads per A row
    constexpr int CA = 32 / TPRA;     // shorts per thread (A)
    int arow = tid / TPRA, acol = (tid % TPRA) * CA;
    constexpr int TPRB = 256 / BN;
    constexpr int CB = 32 / TPRB;
    int brow = tid / TPRB, bcol = (tid % TPRB) * CB;

    for (int k0 = 0; k0 < K; k0 += 32) {
#pragma unroll
        for (int c = 0; c < CA / 8; c++)
            *(s8v*)&Al[arow * 34 + acol + c * 8] =
                *(const s8v*)&A[(size_t)(m0 + arow) * K + k0 + acol + c * 8];
#pragma unroll
        for (int c = 0; c < CB / 8; c++)
            *(s8v*)&Bl[brow * 34 + bcol + c * 8] =
                *(const s8v*)&Bt[(size_t)(n0 + brow) * K + k0 + bcol + c * 8];
        __syncthreads();
        s8v af[MI], bf[NJ];
#pragma unroll
        for (int i = 0; i < MI; i++)
            af[i] = *(const s8v*)&Al[(wm * (BM / 2) + 16 * i + l16) * 34 + quad * 8];
#pragma unroll
        for (int j = 0; j < NJ; j++)
            bf[j] = *(const s8v*)&Bl[(wn * (BN / 2) + 16 * j + l16) * 34 + quad * 8];
#pragma unroll
        for (int i = 0; i < MI; i++)
#pragma unroll
            for (int j = 0; j < NJ; j++)
                acc[i][j] = __builtin_amdgcn_mfma_f32_16x16x32_bf16(af[i], bf[j], acc[i][j], 0, 0, 0);
        __syncthreads();
    }
#pragma unroll
    for (int i = 0; i < MI; i++) {
#pragma unroll
        for (int j = 0; j < NJ; j++) {
            int gc = n0 + wn * (BN / 2) + 16 * j + l16;
            float bz = bias[gc];
#pragma unroll
            for (int r2 = 0; r2 < 4; r2++) {
                int gr = m0 + wm * (BM / 2) + 16 * i + quad * 4 + r2;
                float v = acc[i][j][r2] + bz;
                if (EPI == 1) v = 0.5f * v * (1.0f + erff(v * 0.70710678118f));
                if (EPI == 2) {
                    size_t o = (size_t)gr * N + gc;
                    X[o] = X[o] + v;
                } else if (EPI == 3) {
                    X[(size_t)gr * N + gc] = v;
                } else {
                    C[(size_t)gr * N + gc] = f2bs(v);
                }
            }
        }
    }
}

// ---------------- fallback GEMM (fp32 W, converts in-kernel) ----------------
template <int EPI>
__global__ __launch_bounds__(256) void gemm_w32_k(const short* __restrict__ A,
                                                  const float* __restrict__ W,
                                                  const float* __restrict__ bias,
                                                  short* __restrict__ C,
                                                  float* __restrict__ X, int M, int N, int K) {
    __shared__ short Al[64 * 32];
    __shared__ short Bl[32 * 66];
    int tid = threadIdx.x, lane = tid & 63, wave = tid >> 6;
    int wm = wave >> 1, wn = wave & 1;
    int quad = lane >> 4, l16 = lane & 15;
    int m0 = blockIdx.y * 64, n0 = blockIdx.x * 64;
    f4v acc[2][2];
#pragma unroll
    for (int i = 0; i < 2; i++)
#pragma unroll
        for (int j = 0; j < 2; j++) acc[i][j] = (f4v){0.f, 0.f, 0.f, 0.f};
    int arow = tid >> 2, acol = (tid & 3) * 8;
    int brow = tid >> 3, bcol = (tid & 7) * 8;
    for (int k0 = 0; k0 < K; k0 += 32) {
        *(s8v*)&Al[arow * 32 + acol] = *(const s8v*)&A[(size_t)(m0 + arow) * K + k0 + acol];
        const float* wp = &W[(size_t)(k0 + brow) * N + n0 + bcol];
        f4v wa = *(const f4v*)wp;
        f4v wb = *(const f4v*)(wp + 4);
#pragma unroll
        for (int j = 0; j < 4; j++) {
            Bl[brow * 66 + bcol + j] = f2bs(wa[j]);
            Bl[brow * 66 + bcol + 4 + j] = f2bs(wb[j]);
        }
        __syncthreads();
        s8v af[2], bf[2];
#pragma unroll
        for (int i = 0; i < 2; i++)
            af[i] = *(const s8v*)&Al[(32 * wm + 16 * i + l16) * 32 + quad * 8];
#pragma unroll
        for (int j = 0; j < 2; j++) {
            s8v t;
#pragma unroll
            for (int u = 0; u < 8; u++)
                t[u] = Bl[(quad * 8 + u) * 66 + 32 * wn + 16 * j + l16];
            bf[j] = t;
        }
#pragma unroll
        for (int i = 0; i < 2; i++)
#pragma unroll
            for (int j = 0; j < 2; j++)
                acc[i][j] = __builtin_amdgcn_mfma_f32_16x16x32_bf16(af[i], bf[j], acc[i][j], 0, 0, 0);
        __syncthreads();
    }
#pragma unroll
    for (int i = 0; i < 2; i++) {
#pragma unroll
        for (int j = 0; j < 2; j++) {
            int gc = n0 + 32 * wn + 16 * j + l16;
            float bz = bias[gc];
#pragma unroll
            for (int r = 0; r < 4; r++) {
                int gr = m0 + 32 * wm + 16 * i + quad * 4 + r;
                float v = acc[i][j][r] + bz;
                if (EPI == 1) v = 0.5f * v * (1.0f + erff(v * 0.70710678118f));
                if (EPI == 2) {
                    size_t o = (size_t)gr * N + gc;
                    X[o] = X[o] + v;
                } else if (EPI == 3) {
                    X[(size_t)gr * N + gc] = v;
                } else {
                    C[(size_t)gr * N + gc] = f2bs(v);
                }
            }
        }
    }
}

// ---------------- self-attention (causal), one (b,h,row-group-of-32) per block ----------------
__global__ __launch_bounds__(256) void sattn_k(const short* __restrict__ qkv,
                                               short* __restrict__ attn) {
    int grp = blockIdx.x;   // 0..3 (32 query rows each)
    int bh = blockIdx.y;    // b*H + h
    int b = bh >> 3, h = bh & 7;
    __shared__ short Kl[128 * 66];
    __shared__ short Vl[128 * 66];
    __shared__ short Ql[32 * 66];
    __shared__ float pl[4][128];
    int tid = threadIdx.x, lane = tid & 63, wave = tid >> 6;
    size_t basek = ((size_t)b * TT) * 1536 + 512 + h * 64;
    size_t basev = basek + 512;
    for (int idx = tid; idx < 128 * 64; idx += 256) {
        int j = idx >> 6, d = idx & 63;
        Kl[j * 66 + d] = qkv[basek + (size_t)j * 1536 + d];
        Vl[j * 66 + d] = qkv[basev + (size_t)j * 1536 + d];
    }
    size_t baseq = ((size_t)b * TT + grp * 32) * 1536 + h * 64;
    for (int idx = tid; idx < 32 * 64; idx += 256) {
        int r = idx >> 6, d = idx & 63;
        Ql[r * 66 + d] = qkv[baseq + (size_t)r * 1536 + d];
    }
    __syncthreads();
    for (int i = 0; i < 8; i++) {
        int rl = wave * 8 + i, rg = grp * 32 + rl;
        float s0 = 0.f, s1 = 0.f;
        const short* qrow = &Ql[rl * 66];
        for (int d = 0; d < 64; d++) {
            float qd = bs2f(qrow[d]);
            s0 += qd * bs2f(Kl[lane * 66 + d]);
            s1 += qd * bs2f(Kl[(lane + 64) * 66 + d]);
        }
        s0 = (lane <= rg) ? s0 * 0.125f : -1e30f;
        s1 = (lane + 64 <= rg) ? s1 * 0.125f : -1e30f;
        float m = fmaxf(s0, s1);
        for (int o = 32; o; o >>= 1) m = fmaxf(m, __shfl_xor(m, o, 64));
        float e0 = expf(s0 - m), e1 = expf(s1 - m);
        float sm = e0 + e1;
        for (int o = 32; o; o >>= 1) sm += __shfl_xor(sm, o, 64);
        float inv = 1.0f / sm;
        pl[wave][lane] = e0 * inv;
        pl[wave][lane + 64] = e1 * inv;
        float oa = 0.f;
        for (int j = 0; j < 128; j++) oa += pl[wave][j] * bs2f(Vl[j * 66 + lane]);
        attn[((size_t)b * TT + rg) * DD + h * 64 + lane] = f2bs(oa);
    }
}

// ---------------- cross-attention to memory (256 keys), two-tile online softmax ----------------
__global__ __launch_bounds__(256) void cattn_k(const short* __restrict__ qb,
                                               const short* __restrict__ kvb,
                                               short* __restrict__ attn) {
    int grp = blockIdx.x, bh = blockIdx.y;
    int b = bh >> 3, h = bh & 7;
    __shared__ short Kl[128 * 66];
    __shared__ short Vl[128 * 66];
    __shared__ short Ql[32 * 66];
    __shared__ float pl[4][128];
    int tid = threadIdx.x, lane = tid & 63, wave = tid >> 6;
    float om[8], osum[8], oacc[8];
#pragma unroll
    for (int i = 0; i < 8; i++) { om[i] = -1e30f; osum[i] = 0.f; oacc[i] = 0.f; }

    size_t baseq = ((size_t)b * TT + grp * 32) * DD + h * 64;
    for (int idx = tid; idx < 32 * 64; idx += 256) {
        int r = idx >> 6, d = idx & 63;
        Ql[r * 66 + d] = qb[baseq + (size_t)r * DD + d];
    }
    for (int half = 0; half < 2; half++) {
        __syncthreads();
        size_t basek = ((size_t)b * MM + half * 128) * 1024 + h * 64;
        size_t basev = basek + 512;
        for (int idx = tid; idx < 128 * 64; idx += 256) {
            int j = idx >> 6, d = idx & 63;
            Kl[j * 66 + d] = kvb[basek + (size_t)j * 1024 + d];
            Vl[j * 66 + d] = kvb[basev + (size_t)j * 1024 + d];
        }
        __syncthreads();
        for (int i = 0; i < 8; i++) {
            int rl = wave * 8 + i;
            float s0 = 0.f, s1 = 0.f;
            const short* qrow = &Ql[rl * 66];
            for (int d = 0; d < 64; d++) {
                float qd = bs2f(qrow[d]);
                s0 += qd * bs2f(Kl[lane * 66 + d]);
                s1 += qd * bs2f(Kl[(lane + 64) * 66 + d]);
            }
            s0 *= 0.125f;
            s1 *= 0.125f;
            float m = fmaxf(s0, s1);
            for (int o = 32; o; o >>= 1) m = fmaxf(m, __shfl_xor(m, o, 64));
            float mnew = fmaxf(om[i], m);
            float e0 = expf(s0 - mnew), e1 = expf(s1 - mnew);
            float ps = e0 + e1;
            for (int o = 32; o; o >>= 1) ps += __shfl_xor(ps, o, 64);
            float corr = expf(om[i] - mnew);
            osum[i] = osum[i] * corr + ps;
            oacc[i] = oacc[i] * corr;
            om[i] = mnew;
            pl[wave][lane] = e0;
            pl[wave][lane + 64] = e1;
            float oa = 0.f;
            for (int j = 0; j < 128; j++) oa += pl[wave][j] * bs2f(Vl[j * 66 + lane]);
            oacc[i] += oa;
        }
    }
#pragma unroll
    for (int i = 0; i < 8; i++) {
        int rg = grp * 32 + wave * 8 + i;
        attn[((size_t)b * TT + rg) * DD + h * 64 + lane] = f2bs(oacc[i] / osum[i]);
    }
}

extern "C" void kernel_launch(void* const* d_in, const int* in_sizes, int n_in, void* d_out,
                              int out_size, void* d_ws, size_t ws_size, hipStream_t stream) {
    (void)in_sizes; (void)n_in; (void)out_size;
    typedef const float* fp;
    fp memory = (fp)d_in[0];
    const int* targets = (const int*)d_in[1];
    fp tok = (fp)d_in[2];
    fp pos = (fp)d_in[3];
    fp saqkv_w = (fp)d_in[4], saqkv_b = (fp)d_in[5];
    fp saout_w = (fp)d_in[6], saout_b = (fp)d_in[7];
    fp caq_w = (fp)d_in[8], caq_b = (fp)d_in[9];
    fp cakv_w = (fp)d_in[10], cakv_b = (fp)d_in[11];
    fp caout_w = (fp)d_in[12], caout_b = (fp)d_in[13];
    fp f1w = (fp)d_in[14], f1b = (fp)d_in[15];
    fp f2w = (fp)d_in[16], f2bb = (fp)d_in[17];
    fp ln1g = (fp)d_in[18], ln1b = (fp)d_in[19];
    fp ln2g = (fp)d_in[20], ln2b = (fp)d_in[21];
    fp ln3g = (fp)d_in[22], ln3b = (fp)d_in[23];
    fp lnfg = (fp)d_in[24], lnfb = (fp)d_in[25];
    fp outw = (fp)d_in[26], outb = (fp)d_in[27];
    float* out = (float*)d_out;

    // workspace layout: first 22 MB identical to previous version
    char* ws = (char*)d_ws;
    float* X = (float*)ws;                              //  0..4MB  fp32 residual
    short* Hb = (short*)(ws + (4u << 20));              //  4..6MB  LN output (bf16)
    short* ATT = (short*)(ws + (6u << 20));             //  6..8MB  attn output (bf16)
    short* MEMB = (short*)(ws + (8u << 20));            //  8..12MB memory as bf16
    short* QKV = (short*)(ws + (12u << 20));            // 12..18MB self-attn qkv
    short* Qb = (short*)(ws + (12u << 20));             // 12..14MB cross-attn q (after sattn done)
    short* KVb = (short*)(ws + (14u << 20));            // 14..22MB cross-attn kv
    short* F1 = (short*)(ws + (12u << 20));             // 12..20MB ffn hidden (after cattn done)

    // bf16 transposed-weight area: 22MB.. (~85.3MB total)
    size_t wo = (size_t)22u << 20;
    short* WTqkv = (short*)(ws + wo);                   // L*1536*512  (6291456 B)
    short* WTso  = (short*)(ws + wo + 6291456u);        // L*512*512   (2097152 B)
    short* WTcq  = (short*)(ws + wo + 8388608u);        // L*512*512
    short* WTckv = (short*)(ws + wo + 10485760u);       // L*1024*512  (4194304 B)
    short* WTco  = (short*)(ws + wo + 14680064u);       // L*512*512
    short* WTf1  = (short*)(ws + wo + 16777216u);       // L*2048*512  (8388608 B)
    short* WTf2  = (short*)(ws + wo + 25165824u);       // L*512*2048  (8388608 B)
    short* WTout = (short*)(ws + wo + 33554432u);       // 32000*512   (32768000 B)
    const size_t WS_NEED = wo + 33554432u + 32768000u;  // 89,391,104 B

    const int R = BB * TT;  // 2048
    cvt_k<<<(BB * MM * DD / 4 + 255) / 256, 256, 0, stream>>>(memory, MEMB, BB * MM * DD / 4);
    embed_k<<<R, 256, 0, stream>>>(targets, tok, pos, X);

    if (ws_size >= WS_NEED) {
        // one-time transpose+convert of all weights to bf16 [N,K]
        wt_k<<<dim3(8, 24, LL), 256, 0, stream>>>(saqkv_w, WTqkv, DD, 1536);
        wt_k<<<dim3(8, 8, LL), 256, 0, stream>>>(saout_w, WTso, DD, DD);
        wt_k<<<dim3(8, 8, LL), 256, 0, stream>>>(caq_w, WTcq, DD, DD);
        wt_k<<<dim3(8, 16, LL), 256, 0, stream>>>(cakv_w, WTckv, DD, 1024);
        wt_k<<<dim3(8, 8, LL), 256, 0, stream>>>(caout_w, WTco, DD, DD);
        wt_k<<<dim3(8, 32, LL), 256, 0, stream>>>(f1w, WTf1, DD, 2048);
        wt_k<<<dim3(32, 8, LL), 256, 0, stream>>>(f2w, WTf2, 2048, DD);
        wt_k<<<dim3(8, 500, 1), 256, 0, stream>>>(outw, WTout, DD, VV);

        for (int l = 0; l < LL; l++) {
            ln_k<<<R, 256, 0, stream>>>(X, ln1g + l * DD, ln1b + l * DD, Hb);
            gemm_k<0, 128, 64><<<dim3(R / 128, 1536 / 64), 256, 0, stream>>>(
                Hb, WTqkv + (size_t)l * 1536 * DD, saqkv_b + l * 1536, QKV, nullptr, R, 1536, DD);
            sattn_k<<<dim3(4, BB * HH), 256, 0, stream>>>(QKV, ATT);
            gemm_k<2, 64, 64><<<dim3(R / 64, DD / 64), 256, 0, stream>>>(
                ATT, WTso + (size_t)l * DD * DD, saout_b + l * DD, nullptr, X, R, DD, DD);
            ln_k<<<R, 256, 0, stream>>>(X, ln2g + l * DD, ln2b + l * DD, Hb);
            gemm_k<0, 64, 64><<<dim3(R / 64, DD / 64), 256, 0, stream>>>(
                Hb, WTcq + (size_t)l * DD * DD, caq_b + l * DD, Qb, nullptr, R, DD, DD);
            gemm_k<0, 128, 128><<<dim3((BB * MM) / 128, 1024 / 128), 256, 0, stream>>>(
                MEMB, WTckv + (size_t)l * 1024 * DD, cakv_b + l * 1024, KVb, nullptr, BB * MM, 1024, DD);
            cattn_k<<<dim3(4, BB * HH), 256, 0, stream>>>(Qb, KVb, ATT);
            gemm_k<2, 64, 64><<<dim3(R / 64, DD / 64), 256, 0, stream>>>(
                ATT, WTco + (size_t)l * DD * DD, caout_b + l * DD, nullptr, X, R, DD, DD);
            ln_k<<<R, 256, 0, stream>>>(X, ln3g + l * DD, ln3b + l * DD, Hb);
            gemm_k<1, 128, 128><<<dim3(R / 128, 2048 / 128), 256, 0, stream>>>(
                Hb, WTf1 + (size_t)l * 2048 * DD, f1b + l * 2048, F1, nullptr, R, 2048, DD);
            gemm_k<2, 64, 64><<<dim3(R / 64, DD / 64), 256, 0, stream>>>(
                F1, WTf2 + (size_t)l * DD * 2048, f2bb + l * DD, nullptr, X, R, DD, 2048);
        }
        ln_k<<<R, 256, 0, stream>>>(X, lnfg, lnfb, Hb);
        gemm_k<3, 128, 128><<<dim3(R / 128, VV / 128), 256, 0, stream>>>(
            Hb, WTout, outb, nullptr, out, R, VV, DD);
    } else {
        // fallback: previous fp32-weight path (workspace too small for bf16 weights)
        for (int l = 0; l < LL; l++) {
            ln_k<<<R, 256, 0, stream>>>(X, ln1g + l * DD, ln1b + l * DD, Hb);
            gemm_w32_k<0><<<dim3(1536 / 64, R / 64), 256, 0, stream>>>(
                Hb, saqkv_w + (size_t)l * DD * 1536, saqkv_b + l * 1536, QKV, nullptr, R, 1536, DD);
            sattn_k<<<dim3(4, BB * HH), 256, 0, stream>>>(QKV, ATT);
            gemm_w32_k<2><<<dim3(DD / 64, R / 64), 256, 0, stream>>>(
                ATT, saout_w + (size_t)l * DD * DD, saout_b + l * DD, nullptr, X, R, DD, DD);
            ln_k<<<R, 256, 0, stream>>>(X, ln2g + l * DD, ln2b + l * DD, Hb);
            gemm_w32_k<0><<<dim3(DD / 64, R / 64), 256, 0, stream>>>(
                Hb, caq_w + (size_t)l * DD * DD, caq_b + l * DD, Qb, nullptr, R, DD, DD);
            gemm_w32_k<0><<<dim3(1024 / 64, (BB * MM) / 64), 256, 0, stream>>>(
                MEMB, cakv_w + (size_t)l * DD * 1024, cakv_b + l * 1024, KVb, nullptr, BB * MM, 1024, DD);
            cattn_k<<<dim3(4, BB * HH), 256, 0, stream>>>(Qb, KVb, ATT);
            gemm_w32_k<2><<<dim3(DD / 64, R / 64), 256, 0, stream>>>(
                ATT, caout_w + (size_t)l * DD * DD, caout_b + l * DD, nullptr, X, R, DD, DD);
            ln_k<<<R, 256, 0, stream>>>(X, ln3g + l * DD, ln3b + l * DD, Hb);
            gemm_w32_k<1><<<dim3(2048 / 64, R / 64), 256, 0, stream>>>(
                Hb, f1w + (size_t)l * DD * 2048, f1b + l * 2048, F1, nullptr, R, 2048, DD);
            gemm_w32_k<2><<<dim3(DD / 64, R / 64), 256, 0, stream>>>(
                F1, f2w + (size_t)l * 2048 * DD, f2bb + l * DD, nullptr, X, R, DD, 2048);
        }
        ln_k<<<R, 256, 0, stream>>>(X, lnfg, lnfb, Hb);
        gemm_w32_k<3><<<dim3(VV / 64, R / 64), 256, 0, stream>>>(Hb, outw, outb, nullptr, out, R, VV, DD);
    }
}

// Round 3
// 1176.273 us; speedup vs baseline: 1.4764x; 1.2227x over previous
//
#include <hip/hip_runtime.h>
#include <hip/hip_bf16.h>
#include <math.h>

#define BB 16
#define TT 128
#define MM 256
#define DD 512
#define HH 8
#define LL 4
#define VV 32000
#define BOS_TOK 32000

typedef __attribute__((ext_vector_type(8))) short s8v;
typedef __attribute__((ext_vector_type(4))) float f4v;

__device__ __forceinline__ float bs2f(short u) {
    union { unsigned int i; float f; } c;
    c.i = ((unsigned int)(unsigned short)u) << 16;
    return c.f;
}
// fp32 -> bf16 bits, round-to-nearest-even (finite inputs only)
__device__ __forceinline__ short f2bs(float f) {
    union { float f; unsigned int u; } c;
    c.f = f;
    unsigned int r = (c.u + 0x7FFFu + ((c.u >> 16) & 1u)) >> 16;
    return (short)r;
}

// ---------------- convert fp32 -> bf16 bits (for `memory`) ----------------
__global__ __launch_bounds__(256) void cvt_k(const float* __restrict__ src,
                                             short* __restrict__ dst, int n4) {
    int i = (blockIdx.x * 256 + threadIdx.x);
    if (i < n4) {
        f4v v = *(const f4v*)&src[i * 4];
#pragma unroll
        for (int j = 0; j < 4; j++) dst[i * 4 + j] = f2bs(v[j]);
    }
}

// ---------------- transpose+convert weights: fp32 [K,N] -> bf16 [N,K] ----------------
__global__ __launch_bounds__(256) void wt_k(const float* __restrict__ src,
                                            short* __restrict__ dst, int K, int N) {
    __shared__ short t[64][65];
    int k0 = blockIdx.x * 64, n0 = blockIdx.y * 64;
    size_t zo = (size_t)blockIdx.z * K * N;
    int tid = threadIdx.x;
    int kr = tid >> 2;
    int nc = (tid & 3) * 16;
    const float* sp = src + zo + (size_t)(k0 + kr) * N + n0 + nc;
#pragma unroll
    for (int c = 0; c < 4; c++) {
        f4v v = *(const f4v*)(sp + c * 4);
#pragma unroll
        for (int j = 0; j < 4; j++) t[kr][nc + c * 4 + j] = f2bs(v[j]);
    }
    __syncthreads();
    int nr = tid >> 2;
    int kc = (tid & 3) * 16;
    short* dp = dst + zo + (size_t)(n0 + nr) * K + k0 + kc;
#pragma unroll
    for (int c = 0; c < 2; c++) {
        s8v v;
#pragma unroll
        for (int j = 0; j < 8; j++) v[j] = t[kc + c * 8 + j][nr];
        *(s8v*)(dp + c * 8) = v;
    }
}

// ---------------- embedding ----------------
__global__ __launch_bounds__(256) void embed_k(const int* __restrict__ tgt,
                                               const float* __restrict__ tok,
                                               const float* __restrict__ pos,
                                               float* __restrict__ X) {
    int row = blockIdx.x;
    int t = row & (TT - 1);
    int b = row >> 7;
    int idx = (t == 0) ? BOS_TOK : tgt[b * TT + t - 1];
    const float* te = tok + (size_t)idx * DD;
    const float* pe = pos + (size_t)t * DD;
    float* xr = X + (size_t)row * DD;
    for (int d = threadIdx.x; d < DD; d += 256)
        xr[d] = te[d] + pe[d];
}

// ---------------- layernorm: fp32 x -> bf16 h ----------------
__global__ __launch_bounds__(256) void ln_k(const float* __restrict__ X,
                                            const float* __restrict__ g,
                                            const float* __restrict__ bta,
                                            short* __restrict__ H) {
    int row = blockIdx.x;
    int tid = threadIdx.x;
    const float* xr = X + (size_t)row * DD;
    float v0 = xr[tid], v1 = xr[tid + 256];
    float s = v0 + v1, ss = v0 * v0 + v1 * v1;
    for (int o = 32; o; o >>= 1) {
        s += __shfl_xor(s, o, 64);
        ss += __shfl_xor(ss, o, 64);
    }
    __shared__ float r0[4], r1[4];
    int wave = tid >> 6, lane = tid & 63;
    if (lane == 0) { r0[wave] = s; r1[wave] = ss; }
    __syncthreads();
    s = r0[0] + r0[1] + r0[2] + r0[3];
    ss = r1[0] + r1[1] + r1[2] + r1[3];
    float mean = s * (1.0f / DD);
    float var = ss * (1.0f / DD) - mean * mean;
    float rstd = rsqrtf(var + 1e-5f);
    short* hr = H + (size_t)row * DD;
    hr[tid] = f2bs((v0 - mean) * rstd * g[tid] + bta[tid]);
    hr[tid + 256] = f2bs((v1 - mean) * rstd * g[tid + 256] + bta[tid + 256]);
}

// ---------------- GEMM (bf16 A [M,K] @ bf16 Bt [N,K]) ----------------
template <int EPI, int BM, int BN>
__global__ __launch_bounds__(256) void gemm_k(const short* __restrict__ A,
                                              const short* __restrict__ Bt,
                                              const float* __restrict__ bias,
                                              short* __restrict__ C,
                                              float* __restrict__ X, int M, int N, int K) {
    constexpr int MI = BM / 32;
    constexpr int NJ = BN / 32;
    __shared__ short Al[BM * 34];
    __shared__ short Bl[BN * 34];
    int tid = threadIdx.x, lane = tid & 63, wave = tid >> 6;
    int wm = wave >> 1, wn = wave & 1;
    int quad = lane >> 4, l16 = lane & 15;

    int nwg = gridDim.x * gridDim.y;
    int orig = blockIdx.y * gridDim.x + blockIdx.x;
    int q = nwg >> 3, r = nwg & 7;
    int xcd = orig & 7, pos = orig >> 3;
    int wg = (xcd < r ? xcd * (q + 1) : r * (q + 1) + (xcd - r) * q) + pos;
    int mt = wg % gridDim.x, nt = wg / gridDim.x;
    int m0 = mt * BM, n0 = nt * BN;

    f4v acc[MI][NJ];
#pragma unroll
    for (int i = 0; i < MI; i++)
#pragma unroll
        for (int j = 0; j < NJ; j++) acc[i][j] = (f4v){0.f, 0.f, 0.f, 0.f};

    constexpr int TPRA = 256 / BM;
    constexpr int CA = 32 / TPRA;
    int arow = tid / TPRA, acol = (tid % TPRA) * CA;
    constexpr int TPRB = 256 / BN;
    constexpr int CB = 32 / TPRB;
    int brow = tid / TPRB, bcol = (tid % TPRB) * CB;

    for (int k0 = 0; k0 < K; k0 += 32) {
#pragma unroll
        for (int c = 0; c < CA / 8; c++)
            *(s8v*)&Al[arow * 34 + acol + c * 8] =
                *(const s8v*)&A[(size_t)(m0 + arow) * K + k0 + acol + c * 8];
#pragma unroll
        for (int c = 0; c < CB / 8; c++)
            *(s8v*)&Bl[brow * 34 + bcol + c * 8] =
                *(const s8v*)&Bt[(size_t)(n0 + brow) * K + k0 + bcol + c * 8];
        __syncthreads();
        s8v af[MI], bf[NJ];
#pragma unroll
        for (int i = 0; i < MI; i++)
            af[i] = *(const s8v*)&Al[(wm * (BM / 2) + 16 * i + l16) * 34 + quad * 8];
#pragma unroll
        for (int j = 0; j < NJ; j++)
            bf[j] = *(const s8v*)&Bl[(wn * (BN / 2) + 16 * j + l16) * 34 + quad * 8];
#pragma unroll
        for (int i = 0; i < MI; i++)
#pragma unroll
            for (int j = 0; j < NJ; j++)
                acc[i][j] = __builtin_amdgcn_mfma_f32_16x16x32_bf16(af[i], bf[j], acc[i][j], 0, 0, 0);
        __syncthreads();
    }
#pragma unroll
    for (int i = 0; i < MI; i++) {
#pragma unroll
        for (int j = 0; j < NJ; j++) {
            int gc = n0 + wn * (BN / 2) + 16 * j + l16;
            float bz = bias[gc];
#pragma unroll
            for (int r2 = 0; r2 < 4; r2++) {
                int gr = m0 + wm * (BM / 2) + 16 * i + quad * 4 + r2;
                float v = acc[i][j][r2] + bz;
                if (EPI == 1) v = 0.5f * v * (1.0f + erff(v * 0.70710678118f));
                if (EPI == 2) {
                    size_t o = (size_t)gr * N + gc;
                    X[o] = X[o] + v;
                } else if (EPI == 3) {
                    X[(size_t)gr * N + gc] = v;
                } else {
                    C[(size_t)gr * N + gc] = f2bs(v);
                }
            }
        }
    }
}

// ---------------- fallback GEMM (fp32 W, converts in-kernel) ----------------
template <int EPI>
__global__ __launch_bounds__(256) void gemm_w32_k(const short* __restrict__ A,
                                                  const float* __restrict__ W,
                                                  const float* __restrict__ bias,
                                                  short* __restrict__ C,
                                                  float* __restrict__ X, int M, int N, int K) {
    __shared__ short Al[64 * 32];
    __shared__ short Bl[32 * 66];
    int tid = threadIdx.x, lane = tid & 63, wave = tid >> 6;
    int wm = wave >> 1, wn = wave & 1;
    int quad = lane >> 4, l16 = lane & 15;
    int m0 = blockIdx.y * 64, n0 = blockIdx.x * 64;
    f4v acc[2][2];
#pragma unroll
    for (int i = 0; i < 2; i++)
#pragma unroll
        for (int j = 0; j < 2; j++) acc[i][j] = (f4v){0.f, 0.f, 0.f, 0.f};
    int arow = tid >> 2, acol = (tid & 3) * 8;
    int brow = tid >> 3, bcol = (tid & 7) * 8;
    for (int k0 = 0; k0 < K; k0 += 32) {
        *(s8v*)&Al[arow * 32 + acol] = *(const s8v*)&A[(size_t)(m0 + arow) * K + k0 + acol];
        const float* wp = &W[(size_t)(k0 + brow) * N + n0 + bcol];
        f4v wa = *(const f4v*)wp;
        f4v wb = *(const f4v*)(wp + 4);
#pragma unroll
        for (int j = 0; j < 4; j++) {
            Bl[brow * 66 + bcol + j] = f2bs(wa[j]);
            Bl[brow * 66 + bcol + 4 + j] = f2bs(wb[j]);
        }
        __syncthreads();
        s8v af[2], bf[2];
#pragma unroll
        for (int i = 0; i < 2; i++)
            af[i] = *(const s8v*)&Al[(32 * wm + 16 * i + l16) * 32 + quad * 8];
#pragma unroll
        for (int j = 0; j < 2; j++) {
            s8v t;
#pragma unroll
            for (int u = 0; u < 8; u++)
                t[u] = Bl[(quad * 8 + u) * 66 + 32 * wn + 16 * j + l16];
            bf[j] = t;
        }
#pragma unroll
        for (int i = 0; i < 2; i++)
#pragma unroll
            for (int j = 0; j < 2; j++)
                acc[i][j] = __builtin_amdgcn_mfma_f32_16x16x32_bf16(af[i], bf[j], acc[i][j], 0, 0, 0);
        __syncthreads();
    }
#pragma unroll
    for (int i = 0; i < 2; i++) {
#pragma unroll
        for (int j = 0; j < 2; j++) {
            int gc = n0 + 32 * wn + 16 * j + l16;
            float bz = bias[gc];
#pragma unroll
            for (int r = 0; r < 4; r++) {
                int gr = m0 + 32 * wm + 16 * i + quad * 4 + r;
                float v = acc[i][j][r] + bz;
                if (EPI == 1) v = 0.5f * v * (1.0f + erff(v * 0.70710678118f));
                if (EPI == 2) {
                    size_t o = (size_t)gr * N + gc;
                    X[o] = X[o] + v;
                } else if (EPI == 3) {
                    X[(size_t)gr * N + gc] = v;
                } else {
                    C[(size_t)gr * N + gc] = f2bs(v);
                }
            }
        }
    }
}

// ================= MFMA attention =================
// Fragment convention (same as gemm_k, HW-verified): mfma(af, bf) with
// af = A[M,K] rows (row=l16, k=quad*8+u), bf = Bt[N,K] rows (col=l16, k=quad*8+u),
// C frag: row=quad*4+r, col=l16.
template <int NK>
__device__ __forceinline__ void sattn_body(const short* __restrict__ qkv,
                                           short* __restrict__ attn,
                                           short* Ql, short* Kl, short* Vt, short* Pl,
                                           int b, int h) {
    constexpr int QBASE = NK - 64;
    constexpr int NJ = NK / 16;
    constexpr int QS = 72, KS = 72, VS = NK + 8, PS = NK + 8;
    int tid = threadIdx.x, lane = tid & 63, wave = tid >> 6;
    int quad = lane >> 4, l16 = lane & 15;
    size_t baseq = ((size_t)b * TT + QBASE) * 1536 + h * 64;
    size_t basek = ((size_t)b * TT) * 1536 + 512 + h * 64;
    size_t basev = basek + 512;
    // stage Q (64 rows x 64 d)
    {
        int row = tid >> 2, c = (tid & 3) * 16;
        *(s8v*)&Ql[row * QS + c] = *(const s8v*)&qkv[baseq + (size_t)row * 1536 + c];
        *(s8v*)&Ql[row * QS + c + 8] = *(const s8v*)&qkv[baseq + (size_t)row * 1536 + c + 8];
    }
    // stage K (NK rows x 64 d)
    for (int idx = tid; idx < NK * 4; idx += 256) {
        int row = idx >> 2, c = (idx & 3) * 16;
        *(s8v*)&Kl[row * KS + c] = *(const s8v*)&qkv[basek + (size_t)row * 1536 + c];
        *(s8v*)&Kl[row * KS + c + 8] = *(const s8v*)&qkv[basek + (size_t)row * 1536 + c + 8];
    }
    // stage V transposed: Vt[d][key]
    for (int idx = tid; idx < NK * 4; idx += 256) {
        int key = idx >> 2, c = (idx & 3) * 16;
        s8v v0 = *(const s8v*)&qkv[basev + (size_t)key * 1536 + c];
        s8v v1 = *(const s8v*)&qkv[basev + (size_t)key * 1536 + c + 8];
#pragma unroll
        for (int u = 0; u < 8; u++) {
            Vt[(c + u) * VS + key] = v0[u];
            Vt[(c + 8 + u) * VS + key] = v1[u];
        }
    }
    __syncthreads();
    // S = Q K^T  (wave owns 16 query rows)
    s8v af[2];
#pragma unroll
    for (int kc = 0; kc < 2; kc++)
        af[kc] = *(const s8v*)&Ql[(wave * 16 + l16) * QS + kc * 32 + quad * 8];
    f4v s[NJ];
#pragma unroll
    for (int j = 0; j < NJ; j++) s[j] = (f4v){0.f, 0.f, 0.f, 0.f};
#pragma unroll
    for (int j = 0; j < NJ; j++) {
#pragma unroll
        for (int kc = 0; kc < 2; kc++) {
            s8v bf = *(const s8v*)&Kl[(j * 16 + l16) * KS + kc * 32 + quad * 8];
            s[j] = __builtin_amdgcn_mfma_f32_16x16x32_bf16(af[kc], bf, s[j], 0, 0, 0);
        }
    }
    // causal mask + softmax (row = quad*4+r, col = j*16+l16)
    float sum[4];
#pragma unroll
    for (int r = 0; r < 4; r++) {
        int grow = QBASE + wave * 16 + quad * 4 + r;
        float m = -1e30f;
#pragma unroll
        for (int j = 0; j < NJ; j++) {
            int col = j * 16 + l16;
            float v = (col <= grow) ? s[j][r] * 0.125f : -1e30f;
            s[j][r] = v;
            m = fmaxf(m, v);
        }
        for (int o = 8; o; o >>= 1) m = fmaxf(m, __shfl_xor(m, o, 64));
        float sm = 0.f;
#pragma unroll
        for (int j = 0; j < NJ; j++) {
            float e = expf(s[j][r] - m);   // masked lanes: exp(~-1e30) == 0
            s[j][r] = e;
            sm += e;
        }
        for (int o = 8; o; o >>= 1) sm += __shfl_xor(sm, o, 64);
        sum[r] = sm;
    }
    // write unnormalized P (bf16) to LDS
#pragma unroll
    for (int j = 0; j < NJ; j++)
#pragma unroll
        for (int r = 0; r < 4; r++)
            Pl[(wave * 16 + quad * 4 + r) * PS + j * 16 + l16] = f2bs(s[j][r]);
    __syncthreads();
    // O = P V
    f4v o[4];
#pragma unroll
    for (int j2 = 0; j2 < 4; j2++) o[j2] = (f4v){0.f, 0.f, 0.f, 0.f};
#pragma unroll
    for (int kc = 0; kc < NK / 32; kc++) {
        s8v pa = *(const s8v*)&Pl[(wave * 16 + l16) * PS + kc * 32 + quad * 8];
#pragma unroll
        for (int j2 = 0; j2 < 4; j2++) {
            s8v bv = *(const s8v*)&Vt[(j2 * 16 + l16) * VS + kc * 32 + quad * 8];
            o[j2] = __builtin_amdgcn_mfma_f32_16x16x32_bf16(pa, bv, o[j2], 0, 0, 0);
        }
    }
    float inv[4];
#pragma unroll
    for (int r = 0; r < 4; r++) inv[r] = 1.0f / sum[r];
#pragma unroll
    for (int j2 = 0; j2 < 4; j2++)
#pragma unroll
        for (int r = 0; r < 4; r++) {
            int grow = QBASE + wave * 16 + quad * 4 + r;
            attn[((size_t)b * TT + grow) * DD + h * 64 + j2 * 16 + l16] = f2bs(o[j2][r] * inv[r]);
        }
}

__global__ __launch_bounds__(256) void sattn_m(const short* __restrict__ qkv,
                                               short* __restrict__ attn) {
    __shared__ short Ql[64 * 72];
    __shared__ short Kl[128 * 72];
    __shared__ short Vt[64 * 136];
    __shared__ short Pl[64 * 136];
    int bh = blockIdx.x;
    int b = bh >> 3, h = bh & 7;
    if (blockIdx.y == 0)
        sattn_body<64>(qkv, attn, Ql, Kl, Vt, Pl, b, h);
    else
        sattn_body<128>(qkv, attn, Ql, Kl, Vt, Pl, b, h);
}

// Cross-attn: one block = 64 query rows of one (b,h), all 256 memory keys, no mask.
__global__ __launch_bounds__(256) void cattn_m(const short* __restrict__ qb,
                                               const short* __restrict__ kvb,
                                               short* __restrict__ attn) {
    constexpr int NJ = 16;
    constexpr int QS = 72, KS = 72, VS = 264, PS = 264;
    __shared__ short Ql[64 * QS];
    __shared__ short Kl[256 * KS];
    __shared__ short Vt[64 * VS];
    __shared__ short Pl[64 * PS];
    int bh = blockIdx.x, grp = blockIdx.y;
    int b = bh >> 3, h = bh & 7;
    int tid = threadIdx.x, lane = tid & 63, wave = tid >> 6;
    int quad = lane >> 4, l16 = lane & 15;
    size_t baseq = ((size_t)b * TT + grp * 64) * DD + h * 64;
    size_t basek = ((size_t)b * MM) * 1024 + h * 64;
    size_t basev = basek + 512;
    {
        int row = tid >> 2, c = (tid & 3) * 16;
        *(s8v*)&Ql[row * QS + c] = *(const s8v*)&qb[baseq + (size_t)row * DD + c];
        *(s8v*)&Ql[row * QS + c + 8] = *(const s8v*)&qb[baseq + (size_t)row * DD + c + 8];
    }
    for (int idx = tid; idx < 256 * 4; idx += 256) {
        int row = idx >> 2, c = (idx & 3) * 16;
        *(s8v*)&Kl[row * KS + c] = *(const s8v*)&kvb[basek + (size_t)row * 1024 + c];
        *(s8v*)&Kl[row * KS + c + 8] = *(const s8v*)&kvb[basek + (size_t)row * 1024 + c + 8];
    }
    for (int idx = tid; idx < 256 * 4; idx += 256) {
        int key = idx >> 2, c = (idx & 3) * 16;
        s8v v0 = *(const s8v*)&kvb[basev + (size_t)key * 1024 + c];
        s8v v1 = *(const s8v*)&kvb[basev + (size_t)key * 1024 + c + 8];
#pragma unroll
        for (int u = 0; u < 8; u++) {
            Vt[(c + u) * VS + key] = v0[u];
            Vt[(c + 8 + u) * VS + key] = v1[u];
        }
    }
    __syncthreads();
    s8v af[2];
#pragma unroll
    for (int kc = 0; kc < 2; kc++)
        af[kc] = *(const s8v*)&Ql[(wave * 16 + l16) * QS + kc * 32 + quad * 8];
    f4v s[NJ];
#pragma unroll
    for (int j = 0; j < NJ; j++) s[j] = (f4v){0.f, 0.f, 0.f, 0.f};
#pragma unroll
    for (int j = 0; j < NJ; j++) {
#pragma unroll
        for (int kc = 0; kc < 2; kc++) {
            s8v bf = *(const s8v*)&Kl[(j * 16 + l16) * KS + kc * 32 + quad * 8];
            s[j] = __builtin_amdgcn_mfma_f32_16x16x32_bf16(af[kc], bf, s[j], 0, 0, 0);
        }
    }
    float sum[4];
#pragma unroll
    for (int r = 0; r < 4; r++) {
        float m = -1e30f;
#pragma unroll
        for (int j = 0; j < NJ; j++) {
            float v = s[j][r] * 0.125f;
            s[j][r] = v;
            m = fmaxf(m, v);
        }
        for (int o = 8; o; o >>= 1) m = fmaxf(m, __shfl_xor(m, o, 64));
        float sm = 0.f;
#pragma unroll
        for (int j = 0; j < NJ; j++) {
            float e = expf(s[j][r] - m);
            s[j][r] = e;
            sm += e;
        }
        for (int o = 8; o; o >>= 1) sm += __shfl_xor(sm, o, 64);
        sum[r] = sm;
    }
#pragma unroll
    for (int j = 0; j < NJ; j++)
#pragma unroll
        for (int r = 0; r < 4; r++)
            Pl[(wave * 16 + quad * 4 + r) * PS + j * 16 + l16] = f2bs(s[j][r]);
    __syncthreads();
    f4v o[4];
#pragma unroll
    for (int j2 = 0; j2 < 4; j2++) o[j2] = (f4v){0.f, 0.f, 0.f, 0.f};
#pragma unroll
    for (int kc = 0; kc < 8; kc++) {
        s8v pa = *(const s8v*)&Pl[(wave * 16 + l16) * PS + kc * 32 + quad * 8];
#pragma unroll
        for (int j2 = 0; j2 < 4; j2++) {
            s8v bv = *(const s8v*)&Vt[(j2 * 16 + l16) * VS + kc * 32 + quad * 8];
            o[j2] = __builtin_amdgcn_mfma_f32_16x16x32_bf16(pa, bv, o[j2], 0, 0, 0);
        }
    }
    float inv[4];
#pragma unroll
    for (int r = 0; r < 4; r++) inv[r] = 1.0f / sum[r];
#pragma unroll
    for (int j2 = 0; j2 < 4; j2++)
#pragma unroll
        for (int r = 0; r < 4; r++) {
            int grow = grp * 64 + wave * 16 + quad * 4 + r;
            attn[((size_t)b * TT + grow) * DD + h * 64 + j2 * 16 + l16] = f2bs(o[j2][r] * inv[r]);
        }
}

extern "C" void kernel_launch(void* const* d_in, const int* in_sizes, int n_in, void* d_out,
                              int out_size, void* d_ws, size_t ws_size, hipStream_t stream) {
    (void)in_sizes; (void)n_in; (void)out_size;
    typedef const float* fp;
    fp memory = (fp)d_in[0];
    const int* targets = (const int*)d_in[1];
    fp tok = (fp)d_in[2];
    fp pos = (fp)d_in[3];
    fp saqkv_w = (fp)d_in[4], saqkv_b = (fp)d_in[5];
    fp saout_w = (fp)d_in[6], saout_b = (fp)d_in[7];
    fp caq_w = (fp)d_in[8], caq_b = (fp)d_in[9];
    fp cakv_w = (fp)d_in[10], cakv_b = (fp)d_in[11];
    fp caout_w = (fp)d_in[12], caout_b = (fp)d_in[13];
    fp f1w = (fp)d_in[14], f1b = (fp)d_in[15];
    fp f2w = (fp)d_in[16], f2bb = (fp)d_in[17];
    fp ln1g = (fp)d_in[18], ln1b = (fp)d_in[19];
    fp ln2g = (fp)d_in[20], ln2b = (fp)d_in[21];
    fp ln3g = (fp)d_in[22], ln3b = (fp)d_in[23];
    fp lnfg = (fp)d_in[24], lnfb = (fp)d_in[25];
    fp outw = (fp)d_in[26], outb = (fp)d_in[27];
    float* out = (float*)d_out;

    char* ws = (char*)d_ws;
    float* X = (float*)ws;                              //  0..4MB  fp32 residual
    short* Hb = (short*)(ws + (4u << 20));              //  4..6MB  LN output (bf16)
    short* ATT = (short*)(ws + (6u << 20));             //  6..8MB  attn output (bf16)
    short* MEMB = (short*)(ws + (8u << 20));            //  8..12MB memory as bf16
    short* QKV = (short*)(ws + (12u << 20));            // 12..18MB self-attn qkv
    short* Qb = (short*)(ws + (12u << 20));             // 12..14MB cross-attn q (after sattn done)
    short* KVb = (short*)(ws + (14u << 20));            // 14..22MB cross-attn kv
    short* F1 = (short*)(ws + (12u << 20));             // 12..20MB ffn hidden (after cattn done)

    size_t wo = (size_t)22u << 20;
    short* WTqkv = (short*)(ws + wo);                   // L*1536*512
    short* WTso  = (short*)(ws + wo + 6291456u);        // L*512*512
    short* WTcq  = (short*)(ws + wo + 8388608u);        // L*512*512
    short* WTckv = (short*)(ws + wo + 10485760u);       // L*1024*512
    short* WTco  = (short*)(ws + wo + 14680064u);       // L*512*512
    short* WTf1  = (short*)(ws + wo + 16777216u);       // L*2048*512
    short* WTf2  = (short*)(ws + wo + 25165824u);       // L*512*2048
    short* WTout = (short*)(ws + wo + 33554432u);       // 32000*512
    const size_t WS_NEED = wo + 33554432u + 32768000u;

    const int R = BB * TT;  // 2048
    cvt_k<<<(BB * MM * DD / 4 + 255) / 256, 256, 0, stream>>>(memory, MEMB, BB * MM * DD / 4);
    embed_k<<<R, 256, 0, stream>>>(targets, tok, pos, X);

    if (ws_size >= WS_NEED) {
        wt_k<<<dim3(8, 24, LL), 256, 0, stream>>>(saqkv_w, WTqkv, DD, 1536);
        wt_k<<<dim3(8, 8, LL), 256, 0, stream>>>(saout_w, WTso, DD, DD);
        wt_k<<<dim3(8, 8, LL), 256, 0, stream>>>(caq_w, WTcq, DD, DD);
        wt_k<<<dim3(8, 16, LL), 256, 0, stream>>>(cakv_w, WTckv, DD, 1024);
        wt_k<<<dim3(8, 8, LL), 256, 0, stream>>>(caout_w, WTco, DD, DD);
        wt_k<<<dim3(8, 32, LL), 256, 0, stream>>>(f1w, WTf1, DD, 2048);
        wt_k<<<dim3(32, 8, LL), 256, 0, stream>>>(f2w, WTf2, 2048, DD);
        wt_k<<<dim3(8, 500, 1), 256, 0, stream>>>(outw, WTout, DD, VV);

        for (int l = 0; l < LL; l++) {
            ln_k<<<R, 256, 0, stream>>>(X, ln1g + l * DD, ln1b + l * DD, Hb);
            gemm_k<0, 128, 64><<<dim3(R / 128, 1536 / 64), 256, 0, stream>>>(
                Hb, WTqkv + (size_t)l * 1536 * DD, saqkv_b + l * 1536, QKV, nullptr, R, 1536, DD);
            sattn_m<<<dim3(BB * HH, 2), 256, 0, stream>>>(QKV, ATT);
            gemm_k<2, 64, 64><<<dim3(R / 64, DD / 64), 256, 0, stream>>>(
                ATT, WTso + (size_t)l * DD * DD, saout_b + l * DD, nullptr, X, R, DD, DD);
            ln_k<<<R, 256, 0, stream>>>(X, ln2g + l * DD, ln2b + l * DD, Hb);
            gemm_k<0, 64, 64><<<dim3(R / 64, DD / 64), 256, 0, stream>>>(
                Hb, WTcq + (size_t)l * DD * DD, caq_b + l * DD, Qb, nullptr, R, DD, DD);
            gemm_k<0, 128, 128><<<dim3((BB * MM) / 128, 1024 / 128), 256, 0, stream>>>(
                MEMB, WTckv + (size_t)l * 1024 * DD, cakv_b + l * 1024, KVb, nullptr, BB * MM, 1024, DD);
            cattn_m<<<dim3(BB * HH, 2), 256, 0, stream>>>(Qb, KVb, ATT);
            gemm_k<2, 64, 64><<<dim3(R / 64, DD / 64), 256, 0, stream>>>(
                ATT, WTco + (size_t)l * DD * DD, caout_b + l * DD, nullptr, X, R, DD, DD);
            ln_k<<<R, 256, 0, stream>>>(X, ln3g + l * DD, ln3b + l * DD, Hb);
            gemm_k<1, 128, 128><<<dim3(R / 128, 2048 / 128), 256, 0, stream>>>(
                Hb, WTf1 + (size_t)l * 2048 * DD, f1b + l * 2048, F1, nullptr, R, 2048, DD);
            gemm_k<2, 64, 64><<<dim3(R / 64, DD / 64), 256, 0, stream>>>(
                F1, WTf2 + (size_t)l * DD * 2048, f2bb + l * DD, nullptr, X, R, DD, 2048);
        }
        ln_k<<<R, 256, 0, stream>>>(X, lnfg, lnfb, Hb);
        gemm_k<3, 128, 128><<<dim3(R / 128, VV / 128), 256, 0, stream>>>(
            Hb, WTout, outb, nullptr, out, R, VV, DD);
    } else {
        for (int l = 0; l < LL; l++) {
            ln_k<<<R, 256, 0, stream>>>(X, ln1g + l * DD, ln1b + l * DD, Hb);
            gemm_w32_k<0><<<dim3(1536 / 64, R / 64), 256, 0, stream>>>(
                Hb, saqkv_w + (size_t)l * DD * 1536, saqkv_b + l * 1536, QKV, nullptr, R, 1536, DD);
            sattn_m<<<dim3(BB * HH, 2), 256, 0, stream>>>(QKV, ATT);
            gemm_w32_k<2><<<dim3(DD / 64, R / 64), 256, 0, stream>>>(
                ATT, saout_w + (size_t)l * DD * DD, saout_b + l * DD, nullptr, X, R, DD, DD);
            ln_k<<<R, 256, 0, stream>>>(X, ln2g + l * DD, ln2b + l * DD, Hb);
            gemm_w32_k<0><<<dim3(DD / 64, R / 64), 256, 0, stream>>>(
                Hb, caq_w + (size_t)l * DD * DD, caq_b + l * DD, Qb, nullptr, R, DD, DD);
            gemm_w32_k<0><<<dim3(1024 / 64, (BB * MM) / 64), 256, 0, stream>>>(
                MEMB, cakv_w + (size_t)l * DD * 1024, cakv_b + l * 1024, KVb, nullptr, BB * MM, 1024, DD);
            cattn_m<<<dim3(BB * HH, 2), 256, 0, stream>>>(Qb, KVb, ATT);
            gemm_w32_k<2><<<dim3(DD / 64, R / 64), 256, 0, stream>>>(
                ATT, caout_w + (size_t)l * DD * DD, caout_b + l * DD, nullptr, X, R, DD, DD);
            ln_k<<<R, 256, 0, stream>>>(X, ln3g + l * DD, ln3b + l * DD, Hb);
            gemm_w32_k<1><<<dim3(2048 / 64, R / 64), 256, 0, stream>>>(
                Hb, f1w + (size_t)l * DD * 2048, f1b + l * 2048, F1, nullptr, R, 2048, DD);
            gemm_w32_k<2><<<dim3(DD / 64, R / 64), 256, 0, stream>>>(
                F1, f2w + (size_t)l * 2048 * DD, f2bb + l * DD, nullptr, X, R, DD, 2048);
        }
        ln_k<<<R, 256, 0, stream>>>(X, lnfg, lnfb, Hb);
        gemm_w32_k<3><<<dim3(VV / 64, R / 64), 256, 0, stream>>>(Hb, outw, outb, nullptr, out, R, VV, DD);
    }
}